// Round 21
// baseline (46.288 us; speedup 1.0000x reference)
//
#include <hip/hip_runtime.h>
#include <cmath>

// Local contrast normalization, fused tile kernel (r20 base + r21 batching).
// x: [64,512,512,1] f32. 9x9 Gaussian (separable, center 4.5), SAME zero pad.
// Tile: 64 wide x 32 tall, 256 threads, 25.3 KB LDS (6 blocks/CU).
// r18: dd-prefill (p2 vmem-free). r19/r21: p2 4-row groups (12 h1 reads
// serve 4 outputs). r20: packed fp32 (v_pk_fma_f32). r21: p4 4-row groups
// on 128 threads (final phase -> idle threads exit free). Block LDS
// thread-ops 12.3k -> 9.8k (-20%).

struct W9 { float w[9]; };

typedef float nf4 __attribute__((ext_vector_type(4)));  // nontemporal store
typedef float f2  __attribute__((ext_vector_type(2)));  // packed math

__device__ __forceinline__ f2 ffma2(f2 a, f2 b, f2 c) {
    return __builtin_elementwise_fma(a, b, c);
}

#define HW   512
#define HW4  128   // f4 per image row
#define TSY  32    // output tile height
#define NH1  18    // h1/dd width in f4 (72 cols: ox-4 .. ox+67)
#define NH2  16    // h2/out width in f4 (64 cols)
#define RH1  48    // h1 rows  (oy-8 .. oy+39)
#define RDD  40    // dd/h2 rows (oy-4 .. oy+35)

// horizontal 9-tap on 12 floats -> 4 outputs, packed.
__device__ __forceinline__ float4 conv9h(const float X[12], const float* w) {
    f2 P[11];
#pragma unroll
    for (int k = 0; k < 11; ++k) P[k] = f2{X[k], X[k + 1]};
    f2 lo = {0.f, 0.f}, hi = {0.f, 0.f};
#pragma unroll
    for (int j = 0; j < 9; ++j) {
        const f2 wj = {w[j], w[j]};
        lo = ffma2(wj, P[j], lo);
        hi = ffma2(wj, P[j + 2], hi);
    }
    return float4{lo.x, lo.y, hi.x, hi.y};
}

// ---- p1: load 3 x-f4s for task o (row oy-8+r, cols oxf-2+m..+2) ----
template <bool G>
__device__ __forceinline__ void p1_load(int o, const float* __restrict__ xb,
                                        int oxf, int oy, float4 v[3]) {
    int r = o / NH1, m = o % NH1;
    int gy = oy - 8 + r;
    const float4* row = reinterpret_cast<const float4*>(xb + (size_t)gy * HW);
    bool rowin = !G || ((unsigned)gy < (unsigned)HW);
#pragma unroll
    for (int k = 0; k < 3; ++k) {
        int g4 = oxf - 2 + m + k;
        if (G) v[k] = (rowin && g4 >= 0 && g4 < HW4)
                          ? row[g4] : float4{0.f, 0.f, 0.f, 0.f};
        else   v[k] = row[g4];            // interior: provably in-range
    }
}

// h1[o] = h-conv; stash middle x (col oxf-1+m) into dd for p2 (t = o-72).
__device__ __forceinline__ void p1_fin(int o, const float4 v[3], const float* w,
                                       float4* __restrict__ h1,
                                       float4* __restrict__ dd) {
    const float X[12] = {v[0].x, v[0].y, v[0].z, v[0].w,
                         v[1].x, v[1].y, v[1].z, v[1].w,
                         v[2].x, v[2].y, v[2].z, v[2].w};
    h1[o] = conv9h(X, w);
    if (o >= 4 * NH1 && o < 44 * NH1) dd[o - 4 * NH1] = v[1];
}

// ---- p2 quad: dd rows 4rg..4rg+3, col m. 12 h1 reads -> 4 outputs. ----
template <bool G>
__device__ __forceinline__ void p2_quad(int rg, int m, int oxf, int oy,
                                        const float* w,
                                        const float4* __restrict__ h1,
                                        float4* __restrict__ dd) {
    const int r0 = 4 * rg;
    const int t0 = r0 * NH1 + m;
    float4 xv[4];                         // prefilled x (read before overwrite)
#pragma unroll
    for (int k = 0; k < 4; ++k) xv[k] = dd[t0 + k * NH1];
    f2 hl[12], hh[12];
#pragma unroll
    for (int j = 0; j < 12; ++j) {
        float4 h = h1[t0 + j * NH1];
        hl[j] = f2{h.x, h.y};
        hh[j] = f2{h.z, h.w};
    }
#pragma unroll
    for (int k = 0; k < 4; ++k) {
        f2 ml = {0.f, 0.f}, mh = {0.f, 0.f};
#pragma unroll
        for (int j = 0; j < 9; ++j) {
            const f2 wj = {w[j], w[j]};
            ml = ffma2(wj, hl[k + j], ml);
            mh = ffma2(wj, hh[k + j], mh);
        }
        float4 d = {xv[k].x - ml.x, xv[k].y - ml.y,
                    xv[k].z - mh.x, xv[k].w - mh.y};
        if (G) {
            int g4 = oxf - 1 + m;
            int gy = oy - 4 + r0 + k;
            if (!(((unsigned)g4 < (unsigned)HW4) &&
                  ((unsigned)gy < (unsigned)HW)))
                d = float4{0.f, 0.f, 0.f, 0.f};
        }
        dd[t0 + k * NH1] = d;
    }
}

// ---- p3: h2[o] = h-conv(dd^2); squares packed, conv packed ----
__device__ __forceinline__ void p3_task(int o, const float* w,
                                        const float4* __restrict__ dd,
                                        float4* __restrict__ h2) {
    int r = o / NH2, n = o % NH2;
    float4 a = dd[r * NH1 + n];
    float4 b = dd[r * NH1 + n + 1];
    float4 c = dd[r * NH1 + n + 2];
    f2 s0 = f2{a.x, a.y} * f2{a.x, a.y};
    f2 s1 = f2{a.z, a.w} * f2{a.z, a.w};
    f2 s2 = f2{b.x, b.y} * f2{b.x, b.y};
    f2 s3 = f2{b.z, b.w} * f2{b.z, b.w};
    f2 s4 = f2{c.x, c.y} * f2{c.x, c.y};
    f2 s5 = f2{c.z, c.w} * f2{c.z, c.w};
    const float X[12] = {s0.x, s0.y, s1.x, s1.y, s2.x, s2.y,
                         s3.x, s3.y, s4.x, s4.y, s5.x, s5.y};
    h2[o] = conv9h(X, w);   // o == r*16 + n, contiguous
}

template <bool G>
__device__ __forceinline__ void run_tile(const float* __restrict__ xb,
                                         float* __restrict__ ob,
                                         int oxf, int oy, const float* w,
                                         float4* sm, int tid) {
    float4* h1 = sm;                 // [48][18]
    float4* dd = sm + RH1 * NH1;     // [40][18]
    float4* h2 = sm;                 // [40][16], aliases h1 (dead after p2)

    // ---- p1: 864 tasks; batch the 3 full sweeps' loads, then tail ----
    {
        float4 va[3], vb[3], vc[3];
        p1_load<G>(tid,       xb, oxf, oy, va);
        p1_load<G>(tid + 256, xb, oxf, oy, vb);
        p1_load<G>(tid + 512, xb, oxf, oy, vc);
        p1_fin(tid,       va, w, h1, dd);
        p1_fin(tid + 256, vb, w, h1, dd);
        p1_fin(tid + 512, vc, w, h1, dd);
        if (tid < 96) {
            float4 vd[3];
            p1_load<G>(tid + 768, xb, oxf, oy, vd);
            p1_fin(tid + 768, vd, w, h1, dd);
        }
    }
    __syncthreads();

    // ---- p2: 180 4-row groups (rows partitioned; no cross-thread RMW) ----
    // main 160: m = tid&15 (group-consecutive -> conflict-free), rg = tid>>4.
    if (tid < 160) p2_quad<G>(tid >> 4, tid & 15, oxf, oy, w, h1, dd);
    else if (tid < 180) {
        int i = tid - 160;
        p2_quad<G>(i >> 1, 16 + (i & 1), oxf, oy, w, h1, dd);
    }
    __syncthreads();

    // ---- p3: 640 tasks ----
    p3_task(tid,       w, dd, h2);
    p3_task(tid + 256, w, dd, h2);
    if (tid < 128) p3_task(tid + 512, w, dd, h2);
    __syncthreads();

    // ---- p4: 128 threads x 4-row groups; final phase (idle lanes exit) ----
    if (tid < 128) {
        int n = tid & 15, rg = tid >> 4;   // rg 0..7
        int r0 = 4 * rg;
        f2 rl[12], rh[12];
#pragma unroll
        for (int i = 0; i < 12; ++i) {
            float4 h = h2[(r0 + i) * NH2 + n];
            rl[i] = f2{h.x, h.y};
            rh[i] = f2{h.z, h.w};
        }
#pragma unroll
        for (int k = 0; k < 4; ++k) {
            f2 nl = {0.f, 0.f}, nh = {0.f, 0.f};
#pragma unroll
            for (int j = 0; j < 9; ++j) {
                const f2 wj = {w[j], w[j]};
                nl = ffma2(wj, rl[k + j], nl);
                nh = ffma2(wj, rh[k + j], nh);
            }
            float4 dv = dd[(r0 + k + 4) * NH1 + n + 1];
            nf4 o;  // keep <=> sqrt(n2) > 0.5 <=> n2 > 0.25
            { float nr = rsqrtf(nl.x); o.x = (nl.x > 0.25f) ? dv.x * nr : dv.x; }
            { float nr = rsqrtf(nl.y); o.y = (nl.y > 0.25f) ? dv.y * nr : dv.y; }
            { float nr = rsqrtf(nh.x); o.z = (nh.x > 0.25f) ? dv.z * nr : dv.z; }
            { float nr = rsqrtf(nh.y); o.w = (nh.y > 0.25f) ? dv.w * nr : dv.w; }
            __builtin_nontemporal_store(o,
                reinterpret_cast<nf4*>(ob + (size_t)(oy + r0 + k) * HW) + oxf + n);
        }
    }
}

__global__ __launch_bounds__(256, 6) void lcn_kernel(const float* __restrict__ x,
                                                     float* __restrict__ out,
                                                     W9 wts) {
    __shared__ float4 sm[RH1 * NH1 + RDD * NH1];  // 25,344 B

    const int tid = threadIdx.x;
    const int oxf = blockIdx.x * NH2;
    const int oy  = blockIdx.y * TSY;
    const float* xb = x + (size_t)blockIdx.z * HW * HW;
    float* ob = out + (size_t)blockIdx.z * HW * HW;

    float w[9];
#pragma unroll
    for (int i = 0; i < 9; ++i) w[i] = wts.w[i];

    // interior: x f4-range [oxf-2, oxf+19] in-image for bx 1..6;
    // y-range [oy-8, oy+39] in-image for by 1..14.
    const bool interior = (blockIdx.x > 0 && blockIdx.x < gridDim.x - 1 &&
                           blockIdx.y > 0 && blockIdx.y < gridDim.y - 1);
    if (interior) run_tile<false>(xb, ob, oxf, oy, w, sm, tid);
    else          run_tile<true >(xb, ob, oxf, oy, w, sm, tid);
}

static W9 make_w() {
    // reference: sigmah = 9/6, exponent divides by 2*sigmah = 3.0;
    // taps centered at 4.5 (asymmetric); separable: w1 = g1 / sum(g1).
    double g[9], s = 0.0;
    for (int i = 0; i < 9; ++i) {
        double off = (double)i - 4.5;
        g[i] = exp(-(off * off) / 3.0);
        s += g[i];
    }
    W9 r;
    for (int i = 0; i < 9; ++i) r.w[i] = (float)(g[i] / s);
    return r;
}

extern "C" void kernel_launch(void* const* d_in, const int* in_sizes, int n_in,
                              void* d_out, int out_size, void* d_ws, size_t ws_size,
                              hipStream_t stream) {
    const float* x = (const float*)d_in[0];
    float* out = (float*)d_out;
    W9 w = make_w();
    dim3 grid(HW / 64, HW / TSY, 64);  // 8 x 16 x 64
    lcn_kernel<<<grid, dim3(256), 0, stream>>>(x, out, w);
}

// Round 22
// 44.108 us; speedup vs baseline: 1.0494x; 1.0494x over previous
//
#include <hip/hip_runtime.h>
#include <cmath>

// Local contrast normalization, fused tile kernel (r20 — best measured, 44.2 us).
// x: [64,512,512,1] f32. 9x9 Gaussian (separable, center 4.5), SAME zero pad.
// Tile: 64 wide x 32 tall, 256 threads, 25.3 KB LDS (6 blocks/CU).
// r18: dd-prefill (p2 vmem-free). r19: p2 vertical pairs. r20: packed fp32
// (v_pk_fma_f32 via __builtin_elementwise_fma on ext_vector float2).
// r21's deeper batching REVERTED (regressed: fewer active lanes lost more
// than the LDS-op cut gained).

struct W9 { float w[9]; };

typedef float nf4 __attribute__((ext_vector_type(4)));  // nontemporal store
typedef float f2  __attribute__((ext_vector_type(2)));  // packed math

__device__ __forceinline__ f2 ffma2(f2 a, f2 b, f2 c) {
    return __builtin_elementwise_fma(a, b, c);
}

#define HW   512
#define HW4  128   // f4 per image row
#define TSY  32    // output tile height
#define NH1  18    // h1/dd width in f4 (72 cols: ox-4 .. ox+67)
#define NH2  16    // h2/out width in f4 (64 cols)
#define RH1  48    // h1 rows  (oy-8 .. oy+39)
#define RDD  40    // dd/h2 rows (oy-4 .. oy+35)

// horizontal 9-tap on 12 floats -> 4 outputs, packed:
// o.xy taps pairs P[j] = {X[j],X[j+1]}, o.zw taps P[j+2].
__device__ __forceinline__ float4 conv9h(const float X[12], const float* w) {
    f2 P[11];
#pragma unroll
    for (int k = 0; k < 11; ++k) P[k] = f2{X[k], X[k + 1]};
    f2 lo = {0.f, 0.f}, hi = {0.f, 0.f};
#pragma unroll
    for (int j = 0; j < 9; ++j) {
        const f2 wj = {w[j], w[j]};
        lo = ffma2(wj, P[j], lo);
        hi = ffma2(wj, P[j + 2], hi);
    }
    return float4{lo.x, lo.y, hi.x, hi.y};
}

// ---- p1: load 3 x-f4s for task o (row oy-8+r, cols oxf-2+m..+2) ----
template <bool G>
__device__ __forceinline__ void p1_load(int o, const float* __restrict__ xb,
                                        int oxf, int oy, float4 v[3]) {
    int r = o / NH1, m = o % NH1;
    int gy = oy - 8 + r;
    const float4* row = reinterpret_cast<const float4*>(xb + (size_t)gy * HW);
    bool rowin = !G || ((unsigned)gy < (unsigned)HW);
#pragma unroll
    for (int k = 0; k < 3; ++k) {
        int g4 = oxf - 2 + m + k;
        if (G) v[k] = (rowin && g4 >= 0 && g4 < HW4)
                          ? row[g4] : float4{0.f, 0.f, 0.f, 0.f};
        else   v[k] = row[g4];            // interior: provably in-range
    }
}

// h1[o] = h-conv; stash middle x (col oxf-1+m) into dd for p2 (t = o-72).
__device__ __forceinline__ void p1_fin(int o, const float4 v[3], const float* w,
                                       float4* __restrict__ h1,
                                       float4* __restrict__ dd) {
    const float X[12] = {v[0].x, v[0].y, v[0].z, v[0].w,
                         v[1].x, v[1].y, v[1].z, v[1].w,
                         v[2].x, v[2].y, v[2].z, v[2].w};
    h1[o] = conv9h(X, w);
    if (o >= 4 * NH1 && o < 44 * NH1) dd[o - 4 * NH1] = v[1];
}

// ---- p2 pair: dd rows (2rp, 2rp+1), col m. Packed vertical conv. ----
template <bool G>
__device__ __forceinline__ void p2_pair(int rp, int m, int oxf, int oy,
                                        const float* w,
                                        const float4* __restrict__ h1,
                                        float4* __restrict__ dd) {
    const int r = 2 * rp;
    const int t0 = r * NH1 + m;
    float4 xv0 = dd[t0];                  // prefilled x (read before overwrite)
    float4 xv1 = dd[t0 + NH1];
    f2 hl[10], hh[10];
#pragma unroll
    for (int j = 0; j < 10; ++j) {
        float4 h = h1[t0 + j * NH1];
        hl[j] = f2{h.x, h.y};
        hh[j] = f2{h.z, h.w};
    }
    f2 m0l = {0.f, 0.f}, m0h = {0.f, 0.f}, m1l = {0.f, 0.f}, m1h = {0.f, 0.f};
#pragma unroll
    for (int j = 0; j < 9; ++j) {
        const f2 wj = {w[j], w[j]};
        m0l = ffma2(wj, hl[j], m0l);
        m0h = ffma2(wj, hh[j], m0h);
        m1l = ffma2(wj, hl[j + 1], m1l);
        m1h = ffma2(wj, hh[j + 1], m1h);
    }
    float4 d0 = {xv0.x - m0l.x, xv0.y - m0l.y, xv0.z - m0h.x, xv0.w - m0h.y};
    float4 d1 = {xv1.x - m1l.x, xv1.y - m1l.y, xv1.z - m1h.x, xv1.w - m1h.y};
    if (G) {
        int g4 = oxf - 1 + m;
        bool cin = ((unsigned)g4 < (unsigned)HW4);
        int gy0 = oy - 4 + r;
        if (!(cin && (unsigned)gy0 < (unsigned)HW))
            d0 = float4{0.f, 0.f, 0.f, 0.f};
        if (!(cin && (unsigned)(gy0 + 1) < (unsigned)HW))
            d1 = float4{0.f, 0.f, 0.f, 0.f};
    }
    dd[t0] = d0;
    dd[t0 + NH1] = d1;
}

// ---- p3: h2[o] = h-conv(dd^2); squares packed, conv packed ----
__device__ __forceinline__ void p3_task(int o, const float* w,
                                        const float4* __restrict__ dd,
                                        float4* __restrict__ h2) {
    int r = o / NH2, n = o % NH2;
    float4 a = dd[r * NH1 + n];
    float4 b = dd[r * NH1 + n + 1];
    float4 c = dd[r * NH1 + n + 2];
    f2 s0 = f2{a.x, a.y} * f2{a.x, a.y};
    f2 s1 = f2{a.z, a.w} * f2{a.z, a.w};
    f2 s2 = f2{b.x, b.y} * f2{b.x, b.y};
    f2 s3 = f2{b.z, b.w} * f2{b.z, b.w};
    f2 s4 = f2{c.x, c.y} * f2{c.x, c.y};
    f2 s5 = f2{c.z, c.w} * f2{c.z, c.w};
    const float X[12] = {s0.x, s0.y, s1.x, s1.y, s2.x, s2.y,
                         s3.x, s3.y, s4.x, s4.y, s5.x, s5.y};
    h2[o] = conv9h(X, w);   // o == r*16 + n, contiguous
}

template <bool G>
__device__ __forceinline__ void run_tile(const float* __restrict__ xb,
                                         float* __restrict__ ob,
                                         int oxf, int oy, const float* w,
                                         float4* sm, int tid) {
    float4* h1 = sm;                 // [48][18]
    float4* dd = sm + RH1 * NH1;     // [40][18]
    float4* h2 = sm;                 // [40][16], aliases h1 (dead after p2)

    // ---- p1: 864 tasks; batch the 3 full sweeps' loads, then tail ----
    {
        float4 va[3], vb[3], vc[3];
        p1_load<G>(tid,       xb, oxf, oy, va);
        p1_load<G>(tid + 256, xb, oxf, oy, vb);
        p1_load<G>(tid + 512, xb, oxf, oy, vc);
        p1_fin(tid,       va, w, h1, dd);
        p1_fin(tid + 256, vb, w, h1, dd);
        p1_fin(tid + 512, vc, w, h1, dd);
        if (tid < 96) {
            float4 vd[3];
            p1_load<G>(tid + 768, xb, oxf, oy, vd);
            p1_fin(tid + 768, vd, w, h1, dd);
        }
    }
    __syncthreads();

    // ---- p2: 360 vertical pairs ----
    p2_pair<G>(tid >> 4, tid & 15, oxf, oy, w, h1, dd);
    if (tid < 64) p2_pair<G>(16 + (tid >> 4), tid & 15, oxf, oy, w, h1, dd);
    else if (tid < 104) {
        int idx = tid - 64;
        p2_pair<G>(idx >> 1, 16 + (idx & 1), oxf, oy, w, h1, dd);
    }
    __syncthreads();

    // ---- p3: 640 tasks ----
    p3_task(tid,       w, dd, h2);
    p3_task(tid + 256, w, dd, h2);
    if (tid < 128) p3_task(tid + 512, w, dd, h2);
    __syncthreads();

    // ---- p4: n2 = v-conv(h2) packed; out = keep ? dd*rsqrt(n2) : dd ----
    // 512 outputs: n = tid%16 (group-consecutive), 16 row-groups of 2.
    {
        int n = tid % NH2, rg = tid / NH2;
        int r0 = rg * 2;
        f2 rl[10], rh[10];
#pragma unroll
        for (int i = 0; i < 10; ++i) {
            float4 h = h2[(r0 + i) * NH2 + n];
            rl[i] = f2{h.x, h.y};
            rh[i] = f2{h.z, h.w};
        }
#pragma unroll
        for (int k = 0; k < 2; ++k) {
            f2 nl = {0.f, 0.f}, nh = {0.f, 0.f};
#pragma unroll
            for (int j = 0; j < 9; ++j) {
                const f2 wj = {w[j], w[j]};
                nl = ffma2(wj, rl[k + j], nl);
                nh = ffma2(wj, rh[k + j], nh);
            }
            float4 dv = dd[(r0 + k + 4) * NH1 + n + 1];
            nf4 o;  // keep <=> sqrt(n2) > 0.5 <=> n2 > 0.25
            { float nr = rsqrtf(nl.x); o.x = (nl.x > 0.25f) ? dv.x * nr : dv.x; }
            { float nr = rsqrtf(nl.y); o.y = (nl.y > 0.25f) ? dv.y * nr : dv.y; }
            { float nr = rsqrtf(nh.x); o.z = (nh.x > 0.25f) ? dv.z * nr : dv.z; }
            { float nr = rsqrtf(nh.y); o.w = (nh.y > 0.25f) ? dv.w * nr : dv.w; }
            __builtin_nontemporal_store(o,
                reinterpret_cast<nf4*>(ob + (size_t)(oy + r0 + k) * HW) + oxf + n);
        }
    }
}

__global__ __launch_bounds__(256, 6) void lcn_kernel(const float* __restrict__ x,
                                                     float* __restrict__ out,
                                                     W9 wts) {
    __shared__ float4 sm[RH1 * NH1 + RDD * NH1];  // 25,344 B

    const int tid = threadIdx.x;
    const int oxf = blockIdx.x * NH2;
    const int oy  = blockIdx.y * TSY;
    const float* xb = x + (size_t)blockIdx.z * HW * HW;
    float* ob = out + (size_t)blockIdx.z * HW * HW;

    float w[9];
#pragma unroll
    for (int i = 0; i < 9; ++i) w[i] = wts.w[i];

    // interior: x f4-range [oxf-2, oxf+19] in-image for bx 1..6;
    // y-range [oy-8, oy+39] in-image for by 1..14.
    const bool interior = (blockIdx.x > 0 && blockIdx.x < gridDim.x - 1 &&
                           blockIdx.y > 0 && blockIdx.y < gridDim.y - 1);
    if (interior) run_tile<false>(xb, ob, oxf, oy, w, sm, tid);
    else          run_tile<true >(xb, ob, oxf, oy, w, sm, tid);
}

static W9 make_w() {
    // reference: sigmah = 9/6, exponent divides by 2*sigmah = 3.0;
    // taps centered at 4.5 (asymmetric); separable: w1 = g1 / sum(g1).
    double g[9], s = 0.0;
    for (int i = 0; i < 9; ++i) {
        double off = (double)i - 4.5;
        g[i] = exp(-(off * off) / 3.0);
        s += g[i];
    }
    W9 r;
    for (int i = 0; i < 9; ++i) r.w[i] = (float)(g[i] / s);
    return r;
}

extern "C" void kernel_launch(void* const* d_in, const int* in_sizes, int n_in,
                              void* d_out, int out_size, void* d_ws, size_t ws_size,
                              hipStream_t stream) {
    const float* x = (const float*)d_in[0];
    float* out = (float*)d_out;
    W9 w = make_w();
    dim3 grid(HW / 64, HW / TSY, 64);  // 8 x 16 x 64
    lcn_kernel<<<grid, dim3(256), 0, stream>>>(x, out, w);
}